// Round 11
// baseline (322.926 us; speedup 1.0000x reference)
//
#include <hip/hip_runtime.h>
#include <cstdint>

// Problem constants (match reference)
#define TOK 2048
#define HD  1024
#define ID  768
#define NE  32
#define BM  320            // row tile (5 frags x 16 x 4 waves)
#define NPOS (TOK * 4)     // 8192 pairs total, always

typedef unsigned short u16t;
typedef unsigned int   u32t;
typedef __bf16 bf16x8 __attribute__((ext_vector_type(8)));
typedef float  f32x4  __attribute__((ext_vector_type(4)));
typedef u16t   u16x8  __attribute__((ext_vector_type(8)));
typedef u16t   u16x4  __attribute__((ext_vector_type(4)));
typedef float  fvec4  __attribute__((ext_vector_type(4)));

// f32 -> bf16 round-to-nearest-even
__device__ __forceinline__ u16t f2b(float f) {
  u32t u = __float_as_uint(f);
  u32t r = u + 0x7fffu + ((u >> 16) & 1u);
  return (u16t)(r >> 16);
}

// barrier: drain LDS ops only (ds_writes visible), raw barrier, pin scheduler.
// NO vmcnt — global loads stay in flight across it; all vmem waits come from
// compiler-tracked register dependencies (which never over-drain given our
// issue order: wd before afA before afB each iteration).
#define BAR() do { \
    asm volatile("s_waitcnt lgkmcnt(0)" ::: "memory"); \
    __builtin_amdgcn_s_barrier(); \
    __builtin_amdgcn_sched_barrier(0); \
  } while (0)

// -------------------------------------------------------------- k_router ---
__global__ void k_router(const float* __restrict__ x, const float* __restrict__ gw,
                         const float* __restrict__ eb,
                         int* __restrict__ topk_ids, float* __restrict__ topk_w,
                         int* __restrict__ counts) {
  int lane = threadIdx.x & 63;
  int t = blockIdx.x * 4 + (threadIdx.x >> 6);
  const float* xt = x + (size_t)t * HD;
  fvec4 xr[4];
#pragma unroll
  for (int i = 0; i < 4; ++i) xr[i] = *(const fvec4*)(xt + lane * 4 + i * 256);
  float myscore = 0.f;
  for (int e = 0; e < NE; ++e) {
    const float* ge = gw + (size_t)e * HD + lane * 4;
    float s = 0.f;
#pragma unroll
    for (int i = 0; i < 4; ++i) {
      fvec4 g = *(const fvec4*)(ge + i * 256);
      s = fmaf(xr[i][0], g[0], s); s = fmaf(xr[i][1], g[1], s);
      s = fmaf(xr[i][2], g[2], s); s = fmaf(xr[i][3], g[3], s);
    }
#pragma unroll
    for (int off = 32; off; off >>= 1) s += __shfl_xor(s, off);
    if (lane == e) myscore = s;
  }
  float sig = 1.f / (1.f + expf(-myscore));
  float biased = (lane < NE) ? (sig + eb[lane]) : -3.0e38f;
  float wsum = 0.f;
  int ids[4]; float wsv[4];
#pragma unroll
  for (int k = 0; k < 4; ++k) {
    float v = biased; int idx = lane;
#pragma unroll
    for (int off = 32; off; off >>= 1) {
      float ov = __shfl_xor(v, off);
      int   oi = __shfl_xor(idx, off);
      if (ov > v || (ov == v && oi < idx)) { v = ov; idx = oi; }
    }
    ids[k] = idx;
    float sc = __shfl(sig, idx);   // uncorrected sigmoid score is the weight
    wsv[k] = sc; wsum += sc;
    if (lane == idx) biased = -3.0e38f;
  }
  float inv = 1.f / wsum;
#pragma unroll
  for (int k = 0; k < 4; ++k) {
    if (lane == k) {
      topk_ids[t * 4 + k] = ids[k];
      topk_w[t * 4 + k]  = wsv[k] * inv;
      atomicAdd(&counts[ids[k]], 1);
    }
  }
}

// -------------------------------------------------------------- k_bucket ---
__global__ void k_bucket(const int* __restrict__ topk_ids, const float* __restrict__ topk_w,
                         const int* __restrict__ counts, int* __restrict__ offsets,
                         int* __restrict__ pairTok, float* __restrict__ pairW,
                         int* __restrict__ invp) {
  __shared__ int soff[NE + 1];
  __shared__ int scur[NE];
  int tid = threadIdx.x;
  if (tid == 0) {
    int acc = 0;
    for (int e = 0; e < NE; ++e) { soff[e] = acc; acc += counts[e]; }
    soff[NE] = acc;
  }
  if (tid < NE) scur[tid] = 0;
  __syncthreads();
  if (tid <= NE) offsets[tid] = soff[tid];
  for (int p = tid; p < NPOS; p += 256) {
    int e = topk_ids[p];
    int pos = soff[e] + atomicAdd(&scur[e], 1);
    pairTok[pos] = p;          // p = t*4+k
    pairW[pos]   = topk_w[p];
    invp[p]      = pos;
  }
}

// ------------------------------------------------------------- k_permute ---
// Gather + cvt + swizzle x into bucket order ONCE.
// Xp layout per 16-pos chunk c: [s=0..31][g=0..3][r=0..15][16B], chunk=32KB.
__global__ void k_permute(const float* __restrict__ x, const int* __restrict__ pairTok,
                          u16t* __restrict__ Xp) {
  const int c = blockIdx.x;            // 512 chunks
  const int t = threadIdx.x;
  const int r = t & 15;
  const int tok = pairTok[c * 16 + r] >> 2;
  const float* xrow = x + (size_t)tok * HD;
  u16t* outp = Xp + (size_t)c * 16384;
#pragma unroll
  for (int i = 0; i < 8; ++i) {
    int G = t + i * 256;               // granule index in chunk
    int s = G >> 6, g = (G >> 4) & 3;
    const float* src = xrow + s * 32 + g * 8;
    fvec4 a = *(const fvec4*)src, b = *(const fvec4*)(src + 4);
    u16x8 o = { f2b(a[0]), f2b(a[1]), f2b(a[2]), f2b(a[3]),
                f2b(b[0]), f2b(b[1]), f2b(b[2]), f2b(b[3]) };
    *(u16x8*)&outp[(size_t)G * 8] = o;
  }
}

// --------------------------------------------------------------- k_gemm1 ---
// grid (24 col-tiles of 32, 32 experts) = 768 blocks (3/CU), 256 thr / 4 waves.
// Tile 320x32x{w1,w3}, super-step BK=64 (2 micro-steps of 32) -> ONE barrier
// per 64 k's. X frags direct-to-register from swizzled Xp (1-iter lead);
// W through dbuf LDS (1-iter reg lead). Issue order per iter: wd, afA, afB ->
// every register-dep vmcnt wait leaves newer loads in flight.
__launch_bounds__(256, 3)
__global__ void k_gemm1(const u16t* __restrict__ Xp, const float* __restrict__ w1,
                        const float* __restrict__ w3,
                        const int* __restrict__ counts, const int* __restrict__ offsets,
                        const float* __restrict__ pairW,
                        u16t* __restrict__ A) {
  const int e = blockIdx.y;
  const int colbase = blockIdx.x * 32;
  const int count = counts[e];
  const int base  = offsets[e];
  const int tid = threadIdx.x, lane = tid & 63, wv = tid >> 6;
  const int l15 = lane & 15, kcl = lane >> 4;

  // [buf][mat][micro][kc][col*8]  16 KB, conflict-free granule layout
  __shared__ __align__(16) u16t Ws[2][2][2][4][256];
  __shared__ float pw[BM];

  // W staging: thread covers 4 consecutive k-rows x 4 cols
  const int mat_s = tid >> 7;
  const int vv = tid & 127;
  const int col4 = (vv & 7) * 4;
  const int kr = vv >> 3;                        // 0..15 -> k rows 4kr..4kr+3
  const int wm = kr >> 3, wkc = (kr >> 1) & 3, wob = (kr & 1) * 4;
  const float* wp = (mat_s ? w3 : w1) + (size_t)e * HD * ID + colbase + col4;

#define G1_AFLOAD(AF, S) do { \
    _Pragma("unroll") for (int q = 0; q < 5; ++q) \
      AF[q] = *(const u16x8*)((const char*)Xp + xsrc[q] + (u32t)(S) * 1024u); \
  } while (0)
#define G1_WLOAD(SS) do { \
    const float* _s = wp + (size_t)((SS) * 64 + kr * 4) * ID; \
    wd[0] = *(const fvec4*)_s;            wd[1] = *(const fvec4*)(_s + ID); \
    wd[2] = *(const fvec4*)(_s + 2 * ID); wd[3] = *(const fvec4*)(_s + 3 * ID); \
  } while (0)
#define G1_WSTORE(P) do { \
    _Pragma("unroll") for (int c = 0; c < 4; ++c) { \
      u32t p0 = (u32t)f2b(wd[0][c]) | ((u32t)f2b(wd[1][c]) << 16); \
      u32t p1 = (u32t)f2b(wd[2][c]) | ((u32t)f2b(wd[3][c]) << 16); \
      *(u32t*)&Ws[P][mat_s][wm][wkc][(col4 + c) * 8 + wob]     = p0; \
      *(u32t*)&Ws[P][mat_s][wm][wkc][(col4 + c) * 8 + wob + 2] = p1; \
    } } while (0)
#define G1_MFMA(AF, P, M) do { \
    _Pragma("unroll") for (int m2 = 0; m2 < 2; ++m2) \
      _Pragma("unroll") for (int cf = 0; cf < 2; ++cf) { \
        bf16x8 b = *(const bf16x8*)&Ws[P][m2][M][kcl][(cf * 16 + l15) * 8]; \
        _Pragma("unroll") for (int rf = 0; rf < 5; ++rf) \
          acc[rf][cf][m2] = __builtin_amdgcn_mfma_f32_16x16x32_bf16(AF[rf], b, acc[rf][cf][m2], 0, 0, 0); \
      } \
  } while (0)

  for (int r0 = 0; r0 < count; r0 += BM) {
    __syncthreads();   // pw / Ws reuse safety across passes
    {
      int i = r0 + tid;
      pw[tid] = (i < count) ? pairW[base + i] : 0.f;
      if (tid < BM - 256) {
        int i2 = r0 + 256 + tid;
        pw[256 + tid] = (i2 < count) ? pairW[base + i2] : 0.f;
      }
    }
    // per-lane swizzled fragment bases (constant over K)
    u32t xsrc[5];
#pragma unroll
    for (int q = 0; q < 5; ++q) {
      int pos = base + r0 + wv * 80 + q * 16 + l15;
      pos = pos < NPOS ? pos : NPOS - 1;
      xsrc[q] = (u32t)(pos >> 4) * 32768u + (u32t)kcl * 256u + (u32t)(pos & 15) * 16u;
    }

    f32x4 zz = {0.f, 0.f, 0.f, 0.f};
    f32x4 acc[5][2][2];   // [rf][cf][mat]
#pragma unroll
    for (int a = 0; a < 5; ++a)
#pragma unroll
      for (int b = 0; b < 2; ++b) { acc[a][b][0] = zz; acc[a][b][1] = zz; }

    u16x8 afA[5], afB[5];
    fvec4 wd[4];
    // prologue: af micro 0,1 in flight; W(0) -> buf0; W(1) in flight
    G1_AFLOAD(afA, 0);
    G1_AFLOAD(afB, 1);
    G1_WLOAD(0);
    G1_WSTORE(0);          // waits wd(0) only
    G1_WLOAD(1);           // wd = W(1)
    BAR();

    for (int ss = 0; ss < 16; ss += 2) {
      // even iter: MFMA buf0 = W(ss); store W(ss+1)->buf1; issue W(ss+2), af
      G1_WSTORE(1);
      if (ss + 2 < 16) G1_WLOAD(ss + 2);
      G1_MFMA(afA, 0, 0);
      { const int n = (2 * ss + 2 < 32) ? 2 * ss + 2 : 31; G1_AFLOAD(afA, n); }
      G1_MFMA(afB, 0, 1);
      { const int n = (2 * ss + 3 < 32) ? 2 * ss + 3 : 31; G1_AFLOAD(afB, n); }
      BAR();
      // odd iter: MFMA buf1 = W(ss+1); store W(ss+2)->buf0; issue W(ss+3), af
      G1_WSTORE(0);
      if (ss + 3 < 16) G1_WLOAD(ss + 3);
      G1_MFMA(afA, 1, 0);
      { const int n = (2 * ss + 4 < 32) ? 2 * ss + 4 : 31; G1_AFLOAD(afA, n); }
      G1_MFMA(afB, 1, 1);
      { const int n = (2 * ss + 5 < 32) ? 2 * ss + 5 : 31; G1_AFLOAD(afB, n); }
      BAR();
    }

    // epilogue: a = silu(g)*u*pw -> A (bf16, swizzled layout for gemm2)
    const u32t bx512 = (u32t)blockIdx.x * 512u;
#pragma unroll
    for (int rf = 0; rf < 5; ++rf)
#pragma unroll
      for (int ri = 0; ri < 4; ++ri) {
        int row = wv * 80 + rf * 16 + (lane >> 4) * 4 + ri;
        int grow = r0 + row;
        if (grow < count) {
          float wgt = pw[row];
          int pos = base + grow;
          u32t rbase = (u32t)(pos >> 4) * 12288u + bx512 + (u32t)(pos & 15) * 8u;
#pragma unroll
          for (int cf = 0; cf < 2; ++cf) {
            float gg = acc[rf][cf][0][ri];
            float uu = acc[rf][cf][1][ri];
            float a = gg / (1.f + expf(-gg)) * uu * wgt;
            int cc = cf * 16 + l15;
            A[rbase + (u32t)((cc >> 3) & 3) * 128u + (u32t)(cc & 7)] = f2b(a);
          }
        }
      }
  }
#undef G1_AFLOAD
#undef G1_WLOAD
#undef G1_WSTORE
#undef G1_MFMA
}

// --------------------------------------------------------------- k_gemm2 ---
// grid (32 col-tiles of 32, 32 experts) = 1024 blocks (4/CU). Tile 320x32,
// K=768 -> 12 super-steps of BK=64. Same template, one mat.
__launch_bounds__(256, 4)
__global__ void k_gemm2(const u16t* __restrict__ Ab, const float* __restrict__ w2,
                        const int* __restrict__ counts, const int* __restrict__ offsets,
                        float* __restrict__ buf) {
  const int e = blockIdx.y;
  const int colbase = blockIdx.x * 32;
  const int count = counts[e];
  const int base  = offsets[e];
  const int tid = threadIdx.x, lane = tid & 63, wv = tid >> 6;
  const int l15 = lane & 15, kcl = lane >> 4;

  // [buf][micro][kc][col*8]  8 KB
  __shared__ __align__(16) u16t Ws[2][2][4][256];

  // W staging: thread covers 2 consecutive k-rows x 4 cols
  const int col4 = (tid & 7) * 4;
  const int kr = tid >> 3;                       // 0..31 -> k rows 2kr..2kr+1
  const int wm = kr >> 4, wkc = (kr >> 2) & 3, wob = (kr & 3) * 2;
  const float* wp = w2 + (size_t)e * ID * HD + colbase + col4;

#define G2_AFLOAD(AF, S) do { \
    _Pragma("unroll") for (int q = 0; q < 5; ++q) \
      AF[q] = *(const u16x8*)((const char*)Ab + asrc[q] + (u32t)(S) * 1024u); \
  } while (0)
#define G2_WLOAD(SS) do { \
    const float* _s = wp + (size_t)((SS) * 64 + kr * 2) * HD; \
    wd[0] = *(const fvec4*)_s; wd[1] = *(const fvec4*)(_s + HD); \
  } while (0)
#define G2_WSTORE(P) do { \
    _Pragma("unroll") for (int c = 0; c < 4; ++c) { \
      u32t pk = (u32t)f2b(wd[0][c]) | ((u32t)f2b(wd[1][c]) << 16); \
      *(u32t*)&Ws[P][wm][wkc][(col4 + c) * 8 + wob] = pk; \
    } } while (0)
#define G2_MFMA(AF, P, M) do { \
    _Pragma("unroll") for (int cf = 0; cf < 2; ++cf) { \
      bf16x8 b = *(const bf16x8*)&Ws[P][M][kcl][(cf * 16 + l15) * 8]; \
      _Pragma("unroll") for (int rf = 0; rf < 5; ++rf) \
        acc[rf][cf] = __builtin_amdgcn_mfma_f32_16x16x32_bf16(AF[rf], b, acc[rf][cf], 0, 0, 0); \
    } \
  } while (0)

  for (int r0 = 0; r0 < count; r0 += BM) {
    __syncthreads();   // Ws reuse safety across passes
    u32t asrc[5];
#pragma unroll
    for (int q = 0; q < 5; ++q) {
      int pos = base + r0 + wv * 80 + q * 16 + l15;
      pos = pos < NPOS ? pos : NPOS - 1;
      asrc[q] = (u32t)(pos >> 4) * 24576u + (u32t)kcl * 256u + (u32t)(pos & 15) * 16u;
    }

    f32x4 zz = {0.f, 0.f, 0.f, 0.f};
    f32x4 acc[5][2];
#pragma unroll
    for (int a = 0; a < 5; ++a) { acc[a][0] = zz; acc[a][1] = zz; }

    u16x8 afA[5], afB[5];
    fvec4 wd[2];
    G2_AFLOAD(afA, 0);
    G2_AFLOAD(afB, 1);
    G2_WLOAD(0);
    G2_WSTORE(0);
    G2_WLOAD(1);
    BAR();

    for (int ss = 0; ss < 12; ss += 2) {
      G2_WSTORE(1);
      if (ss + 2 < 12) G2_WLOAD(ss + 2);
      G2_MFMA(afA, 0, 0);
      { const int n = (2 * ss + 2 < 24) ? 2 * ss + 2 : 23; G2_AFLOAD(afA, n); }
      G2_MFMA(afB, 0, 1);
      { const int n = (2 * ss + 3 < 24) ? 2 * ss + 3 : 23; G2_AFLOAD(afB, n); }
      BAR();
      G2_WSTORE(0);
      if (ss + 3 < 12) G2_WLOAD(ss + 3);
      G2_MFMA(afA, 1, 0);
      { const int n = (2 * ss + 4 < 24) ? 2 * ss + 4 : 23; G2_AFLOAD(afA, n); }
      G2_MFMA(afB, 1, 1);
      { const int n = (2 * ss + 5 < 24) ? 2 * ss + 5 : 23; G2_AFLOAD(afB, n); }
      BAR();
    }

#pragma unroll
    for (int rf = 0; rf < 5; ++rf)
#pragma unroll
      for (int ri = 0; ri < 4; ++ri) {
        int row = wv * 80 + rf * 16 + (lane >> 4) * 4 + ri;
        int grow = r0 + row;
        if (grow < count) {
#pragma unroll
          for (int cf = 0; cf < 2; ++cf)
            buf[(size_t)(base + grow) * HD + colbase + cf * 16 + l15] = acc[rf][cf][ri];
        }
      }
  }
#undef G2_AFLOAD
#undef G2_WLOAD
#undef G2_WSTORE
#undef G2_MFMA
}

// -------------------------------------------------------------- k_reduce ---
__global__ void k_reduce(const float* __restrict__ buf, const int* __restrict__ invp,
                         float* __restrict__ out) {
  int t = blockIdx.x;
  int col = threadIdx.x * 4;
  int p0 = invp[t * 4 + 0], p1 = invp[t * 4 + 1];
  int p2 = invp[t * 4 + 2], p3 = invp[t * 4 + 3];
  fvec4 s = *(const fvec4*)(buf + (size_t)p0 * HD + col);
  s += *(const fvec4*)(buf + (size_t)p1 * HD + col);
  s += *(const fvec4*)(buf + (size_t)p2 * HD + col);
  s += *(const fvec4*)(buf + (size_t)p3 * HD + col);
  *(fvec4*)(out + (size_t)t * HD + col) = s;
}

// ------------------------------------------------------------------ host ---
extern "C" void kernel_launch(void* const* d_in, const int* in_sizes, int n_in,
                              void* d_out, int out_size, void* d_ws, size_t ws_size,
                              hipStream_t stream) {
  const float* x  = (const float*)d_in[0];
  const float* gw = (const float*)d_in[1];
  const float* w1 = (const float*)d_in[2];
  const float* w3 = (const float*)d_in[3];
  const float* w2 = (const float*)d_in[4];
  const float* eb = (const float*)d_in[5];
  float* out = (float*)d_out;

  char* ws = (char*)d_ws;
  int*   counts   = (int*)(ws);               // [32]   (zeroed)
  int*   offsets  = (int*)(ws + 256);         // [33]
  int*   topk_ids = (int*)(ws + 4096);        // [8192]
  float* topk_w   = (float*)(ws + 36864);     // [8192]
  int*   pairTok  = (int*)(ws + 69632);       // [8192]
  float* pairW    = (float*)(ws + 102400);    // [8192]
  int*   invp     = (int*)(ws + 135168);      // [8192]
  // Region A (33.55 MB): Xp (16.78 MB, dead after gemm1) overlaid by buf (f32)
  u16t*  Xp   = (u16t*)(ws + 262144);
  float* buf  = (float*)(ws + 262144);
  u16t*  Abuf = (u16t*)(ws + 262144 + 33554432);   // 12.58 MB swizzled bf16
  // total ~46.4 MB

  hipMemsetAsync(counts, 0, 4096, stream);
  k_router <<<512, 256, 0, stream>>>(x, gw, eb, topk_ids, topk_w, counts);
  k_bucket <<<1, 256, 0, stream>>>(topk_ids, topk_w, counts, offsets, pairTok, pairW, invp);
  k_permute<<<512, 256, 0, stream>>>(x, pairTok, Xp);
  k_gemm1  <<<dim3(24, 32), 256, 0, stream>>>(Xp, w1, w3, counts, offsets, pairW, Abuf);
  k_gemm2  <<<dim3(32, 32), 256, 0, stream>>>(Abuf, w2, counts, offsets, buf);
  k_reduce <<<2048, 256, 0, stream>>>(buf, invp, out);
}

// Round 12
// 239.452 us; speedup vs baseline: 1.3486x; 1.3486x over previous
//
#include <hip/hip_runtime.h>
#include <cstdint>

// Problem constants (match reference)
#define TOK 2048
#define HD  1024
#define ID  768
#define NE  32
#define BM  320            // row tile (5 frags x 16 x 4 waves)
#define NPOS (TOK * 4)     // 8192 pairs total, always

typedef unsigned short u16t;
typedef unsigned int   u32t;
typedef __bf16 bf16x8 __attribute__((ext_vector_type(8)));
typedef float  f32x4  __attribute__((ext_vector_type(4)));
typedef u16t   u16x8  __attribute__((ext_vector_type(8)));
typedef u16t   u16x4  __attribute__((ext_vector_type(4)));
typedef float  fvec4  __attribute__((ext_vector_type(4)));

// f32 -> bf16 round-to-nearest-even
__device__ __forceinline__ u16t f2b(float f) {
  u32t u = __float_as_uint(f);
  u32t r = u + 0x7fffu + ((u >> 16) & 1u);
  return (u16t)(r >> 16);
}

// barrier: drain LDS ops only (ds_writes visible), raw barrier, pin scheduler.
// NO vmcnt — global loads stay in flight across it; all vmem waits come from
// compiler-tracked register dependencies.
#define BAR() do { \
    asm volatile("s_waitcnt lgkmcnt(0)" ::: "memory"); \
    __builtin_amdgcn_s_barrier(); \
    __builtin_amdgcn_sched_barrier(0); \
  } while (0)

// -------------------------------------------------------------- k_router ---
__global__ void k_router(const float* __restrict__ x, const float* __restrict__ gw,
                         const float* __restrict__ eb,
                         int* __restrict__ topk_ids, float* __restrict__ topk_w,
                         int* __restrict__ counts) {
  int lane = threadIdx.x & 63;
  int t = blockIdx.x * 4 + (threadIdx.x >> 6);
  const float* xt = x + (size_t)t * HD;
  fvec4 xr[4];
#pragma unroll
  for (int i = 0; i < 4; ++i) xr[i] = *(const fvec4*)(xt + lane * 4 + i * 256);
  float myscore = 0.f;
  for (int e = 0; e < NE; ++e) {
    const float* ge = gw + (size_t)e * HD + lane * 4;
    float s = 0.f;
#pragma unroll
    for (int i = 0; i < 4; ++i) {
      fvec4 g = *(const fvec4*)(ge + i * 256);
      s = fmaf(xr[i][0], g[0], s); s = fmaf(xr[i][1], g[1], s);
      s = fmaf(xr[i][2], g[2], s); s = fmaf(xr[i][3], g[3], s);
    }
#pragma unroll
    for (int off = 32; off; off >>= 1) s += __shfl_xor(s, off);
    if (lane == e) myscore = s;
  }
  float sig = 1.f / (1.f + expf(-myscore));
  float biased = (lane < NE) ? (sig + eb[lane]) : -3.0e38f;
  float wsum = 0.f;
  int ids[4]; float wsv[4];
#pragma unroll
  for (int k = 0; k < 4; ++k) {
    float v = biased; int idx = lane;
#pragma unroll
    for (int off = 32; off; off >>= 1) {
      float ov = __shfl_xor(v, off);
      int   oi = __shfl_xor(idx, off);
      if (ov > v || (ov == v && oi < idx)) { v = ov; idx = oi; }
    }
    ids[k] = idx;
    float sc = __shfl(sig, idx);   // uncorrected sigmoid score is the weight
    wsv[k] = sc; wsum += sc;
    if (lane == idx) biased = -3.0e38f;
  }
  float inv = 1.f / wsum;
#pragma unroll
  for (int k = 0; k < 4; ++k) {
    if (lane == k) {
      topk_ids[t * 4 + k] = ids[k];
      topk_w[t * 4 + k]  = wsv[k] * inv;
      atomicAdd(&counts[ids[k]], 1);
    }
  }
}

// -------------------------------------------------------------- k_bucket ---
__global__ void k_bucket(const int* __restrict__ topk_ids, const float* __restrict__ topk_w,
                         const int* __restrict__ counts, int* __restrict__ offsets,
                         int* __restrict__ pairTok, float* __restrict__ pairW,
                         int* __restrict__ invp) {
  __shared__ int soff[NE + 1];
  __shared__ int scur[NE];
  int tid = threadIdx.x;
  if (tid == 0) {
    int acc = 0;
    for (int e = 0; e < NE; ++e) { soff[e] = acc; acc += counts[e]; }
    soff[NE] = acc;
  }
  if (tid < NE) scur[tid] = 0;
  __syncthreads();
  if (tid <= NE) offsets[tid] = soff[tid];
  for (int p = tid; p < NPOS; p += 256) {
    int e = topk_ids[p];
    int pos = soff[e] + atomicAdd(&scur[e], 1);
    pairTok[pos] = p;          // p = t*4+k
    pairW[pos]   = topk_w[p];
    invp[p]      = pos;
  }
}

// ------------------------------------------------------------- k_permute ---
// Gather + cvt + swizzle x into bucket order ONCE.
// Xp layout per 16-pos chunk c: [s=0..31][g=0..3][r=0..15][16B], chunk=32KB.
__global__ void k_permute(const float* __restrict__ x, const int* __restrict__ pairTok,
                          u16t* __restrict__ Xp) {
  const int c = blockIdx.x;            // 512 chunks
  const int t = threadIdx.x;
  const int r = t & 15;
  const int tok = pairTok[c * 16 + r] >> 2;
  const float* xrow = x + (size_t)tok * HD;
  u16t* outp = Xp + (size_t)c * 16384;
#pragma unroll
  for (int i = 0; i < 8; ++i) {
    int G = t + i * 256;               // granule index in chunk
    int s = G >> 6, g = (G >> 4) & 3;
    const float* src = xrow + s * 32 + g * 8;
    fvec4 a = *(const fvec4*)src, b = *(const fvec4*)(src + 4);
    u16x8 o = { f2b(a[0]), f2b(a[1]), f2b(a[2]), f2b(a[3]),
                f2b(b[0]), f2b(b[1]), f2b(b[2]), f2b(b[3]) };
    *(u16x8*)&outp[(size_t)G * 8] = o;
  }
}

// --------------------------------------------------------------- k_gemm1 ---
// 1-D grid 768 blocks (3/CU, all resident), 256 thr / 4 waves.
// XCD/expert co-location swizzle: xcd = id&7 hosts experts 4*xcd..4*xcd+3,
// all 24 col-tiles of an expert on ONE XCD -> DRAM-page-coherent W stream.
// Tile 320x32x{w1,w3}. X frags direct-to-register from swizzled Xp (2-step
// lead); W through dbuf LDS (1-step reg lead). Barrier = lgkmcnt(0) only.
__launch_bounds__(256, 3)
__global__ void k_gemm1(const u16t* __restrict__ Xp, const float* __restrict__ w1,
                        const float* __restrict__ w3,
                        const int* __restrict__ counts, const int* __restrict__ offsets,
                        const float* __restrict__ pairW,
                        u16t* __restrict__ A) {
  const int id = blockIdx.x;
  const int xcd = id & 7, slot = id >> 3;        // 96 slots per XCD
  const int e = xcd * 4 + slot / 24;             // 4 experts per XCD
  const int ct = slot % 24;                      // col-tile 0..23
  const int colbase = ct * 32;
  const int count = counts[e];
  const int base  = offsets[e];
  const int tid = threadIdx.x, lane = tid & 63, wv = tid >> 6;
  const int l15 = lane & 15, kcl = lane >> 4;

  __shared__ __align__(16) u16t Ws[2][2][1024];      // 8 KB [buf][mat][kcs*256+col*8]
  __shared__ float pw[BM];                           // 1280 B

  // W staging role: col-per-thread, one full granule (8 k's)
  const int mat_s = tid >> 7;
  const int v = tid & 127;
  const int wcolL = v & 31;            // local col 0..31
  const int kcs = v >> 5;              // granule 0..3
  const float* wp = (mat_s ? w3 : w1) + (size_t)e * HD * ID
                    + (size_t)(kcs * 8) * ID + colbase + wcolL;

#define G1_AFLOAD(AF, S) do { \
    _Pragma("unroll") for (int q = 0; q < 5; ++q) \
      AF[q] = *(const u16x8*)((const char*)Xp + xsrc[q] + (u32t)(S) * 1024u); \
  } while (0)
#define G1_WLOAD(KB) do { \
    _Pragma("unroll") for (int j = 0; j < 8; ++j) \
      wd[j] = wp[(size_t)((KB) + j) * ID]; \
  } while (0)
#define G1_WSTORE(P) do { \
    u16x8 pk = { f2b(wd[0]), f2b(wd[1]), f2b(wd[2]), f2b(wd[3]), \
                 f2b(wd[4]), f2b(wd[5]), f2b(wd[6]), f2b(wd[7]) }; \
    *(u16x8*)&Ws[P][mat_s][kcs * 256 + wcolL * 8] = pk; \
  } while (0)
#define G1_MFMA(AF, P) do { \
    _Pragma("unroll") for (int m = 0; m < 2; ++m) \
      _Pragma("unroll") for (int cf = 0; cf < 2; ++cf) { \
        bf16x8 b = *(const bf16x8*)&Ws[P][m][kcl * 256 + (cf * 16 + l15) * 8]; \
        _Pragma("unroll") for (int rf = 0; rf < 5; ++rf) \
          acc[rf][cf][m] = __builtin_amdgcn_mfma_f32_16x16x32_bf16(AF[rf], b, acc[rf][cf][m], 0, 0, 0); \
      } \
  } while (0)

  for (int r0 = 0; r0 < count; r0 += BM) {
    __syncthreads();   // pw / Ws reuse safety across passes
    {
      int i = r0 + tid;
      pw[tid] = (i < count) ? pairW[base + i] : 0.f;
      if (tid < BM - 256) {
        int i2 = r0 + 256 + tid;
        pw[256 + tid] = (i2 < count) ? pairW[base + i2] : 0.f;
      }
    }
    // per-lane swizzled fragment bases (constant over K)
    u32t xsrc[5];
#pragma unroll
    for (int q = 0; q < 5; ++q) {
      int pos = base + r0 + wv * 80 + q * 16 + l15;
      pos = pos < NPOS ? pos : NPOS - 1;
      xsrc[q] = (u32t)(pos >> 4) * 32768u + (u32t)kcl * 256u + (u32t)(pos & 15) * 16u;
    }

    f32x4 zz = {0.f, 0.f, 0.f, 0.f};
    f32x4 acc[5][2][2];   // [rf][cf][mat]
#pragma unroll
    for (int a = 0; a < 5; ++a)
#pragma unroll
      for (int b = 0; b < 2; ++b) { acc[a][b][0] = zz; acc[a][b][1] = zz; }

    u16x8 afA[5], afB[5];
    float wd[8];
    // prologue: af(0), af(1) in flight; W(0) -> LDS buf0; W(1) in flight
    G1_AFLOAD(afA, 0);
    G1_AFLOAD(afB, 1);
    G1_WLOAD(0);
    G1_WSTORE(0);          // waits wd(0)
    G1_WLOAD(32);          // W(1)
    BAR();

    for (int s = 0; s < 32; s += 2) {
      // even step s: read Ws[0]=W(s); store W(s+1)->buf1; issue W(s+2), af(s+2)
      G1_WSTORE(1);
      { const int k2 = (s + 2 < 32) ? s + 2 : 31; G1_WLOAD(k2 * 32); }
      G1_MFMA(afA, 0);
      { const int s2 = (s + 2 < 32) ? s + 2 : 31; G1_AFLOAD(afA, s2); }
      BAR();
      // odd step s+1: read Ws[1]=W(s+1); store W(s+2)->buf0; issue W(s+3), af(s+3)
      G1_WSTORE(0);
      { const int k3 = (s + 3 < 32) ? s + 3 : 31; G1_WLOAD(k3 * 32); }
      G1_MFMA(afB, 1);
      { const int s3 = (s + 3 < 32) ? s + 3 : 31; G1_AFLOAD(afB, s3); }
      BAR();
    }

    // epilogue: a = silu(g)*u*pw -> A (bf16, swizzled layout for gemm2)
    const u32t bx512 = (u32t)ct * 512u;
#pragma unroll
    for (int rf = 0; rf < 5; ++rf)
#pragma unroll
      for (int ri = 0; ri < 4; ++ri) {
        int row = wv * 80 + rf * 16 + (lane >> 4) * 4 + ri;
        int grow = r0 + row;
        if (grow < count) {
          float wgt = pw[row];
          int pos = base + grow;
          u32t rbase = (u32t)(pos >> 4) * 12288u + bx512 + (u32t)(pos & 15) * 8u;
#pragma unroll
          for (int cf = 0; cf < 2; ++cf) {
            float gg = acc[rf][cf][0][ri];
            float uu = acc[rf][cf][1][ri];
            float a = gg / (1.f + expf(-gg)) * uu * wgt;
            int cc = cf * 16 + l15;
            A[rbase + (u32t)((cc >> 3) & 3) * 128u + (u32t)(cc & 7)] = f2b(a);
          }
        }
      }
  }
#undef G1_AFLOAD
#undef G1_WLOAD
#undef G1_WSTORE
#undef G1_MFMA
}

// --------------------------------------------------------------- k_gemm2 ---
// 1-D grid 1024 blocks (4/CU, all resident). Same XCD/expert co-location:
// xcd hosts experts 4*xcd..4*xcd+3, each with all 32 col-tiles. Tile 320x32,
// K=768. A fragments direct-to-register from swizzled Abuf; W2 through LDS.
__launch_bounds__(256, 4)
__global__ void k_gemm2(const u16t* __restrict__ Ab, const float* __restrict__ w2,
                        const int* __restrict__ counts, const int* __restrict__ offsets,
                        float* __restrict__ buf) {
  const int id = blockIdx.x;
  const int xcd = id & 7, slot = id >> 3;        // 128 slots per XCD
  const int e = xcd * 4 + slot / 32;             // 4 experts per XCD
  const int colbase = (slot % 32) * 32;
  const int count = counts[e];
  const int base  = offsets[e];
  const int tid = threadIdx.x, lane = tid & 63, wv = tid >> 6;
  const int l15 = lane & 15, kcl = lane >> 4;

  __shared__ __align__(16) u16t Ws[2][1024];       // 4 KB [buf][kcs*256+col*8]

  // W staging: all 256 threads, col + half-granule (4 k's each)
  const int wcolL = tid & 31;
  const int h = tid >> 5;              // 0..7 half-granules
  const float* w2t = w2 + (size_t)e * ID * HD + (size_t)(h * 4) * HD + colbase + wcolL;
  const int wdst = (h >> 1) * 256 + wcolL * 8 + (h & 1) * 4;

#define G2_AFLOAD(AF, S) do { \
    _Pragma("unroll") for (int q = 0; q < 5; ++q) \
      AF[q] = *(const u16x8*)((const char*)Ab + asrc[q] + (u32t)(S) * 1024u); \
  } while (0)
#define G2_WLOAD(KB) do { \
    _Pragma("unroll") for (int j = 0; j < 4; ++j) \
      wd[j] = w2t[(size_t)((KB) + j) * HD]; \
  } while (0)
#define G2_WSTORE(P) do { \
    u16x4 pk = { f2b(wd[0]), f2b(wd[1]), f2b(wd[2]), f2b(wd[3]) }; \
    *(u16x4*)&Ws[P][wdst] = pk; \
  } while (0)
#define G2_MFMA(AF, P) do { \
    _Pragma("unroll") for (int cf = 0; cf < 2; ++cf) { \
      bf16x8 b = *(const bf16x8*)&Ws[P][kcl * 256 + (cf * 16 + l15) * 8]; \
      _Pragma("unroll") for (int rf = 0; rf < 5; ++rf) \
        acc[rf][cf] = __builtin_amdgcn_mfma_f32_16x16x32_bf16(AF[rf], b, acc[rf][cf], 0, 0, 0); \
    } \
  } while (0)

  for (int r0 = 0; r0 < count; r0 += BM) {
    __syncthreads();   // Ws reuse safety across passes
    u32t asrc[5];
#pragma unroll
    for (int q = 0; q < 5; ++q) {
      int pos = base + r0 + wv * 80 + q * 16 + l15;
      pos = pos < NPOS ? pos : NPOS - 1;
      asrc[q] = (u32t)(pos >> 4) * 24576u + (u32t)kcl * 256u + (u32t)(pos & 15) * 16u;
    }

    f32x4 zz = {0.f, 0.f, 0.f, 0.f};
    f32x4 acc[5][2];
#pragma unroll
    for (int a = 0; a < 5; ++a) { acc[a][0] = zz; acc[a][1] = zz; }

    u16x8 afA[5], afB[5];
    float wd[4];
    G2_AFLOAD(afA, 0);
    G2_AFLOAD(afB, 1);
    G2_WLOAD(0);
    G2_WSTORE(0);
    G2_WLOAD(32);
    BAR();

    for (int s = 0; s < 24; s += 2) {
      G2_WSTORE(1);
      { const int k2 = (s + 2 < 24) ? s + 2 : 23; G2_WLOAD(k2 * 32); }
      G2_MFMA(afA, 0);
      { const int s2 = (s + 2 < 24) ? s + 2 : 23; G2_AFLOAD(afA, s2); }
      BAR();
      G2_WSTORE(0);
      { const int k3 = (s + 3 < 24) ? s + 3 : 23; G2_WLOAD(k3 * 32); }
      G2_MFMA(afB, 1);
      { const int s3 = (s + 3 < 24) ? s + 3 : 23; G2_AFLOAD(afB, s3); }
      BAR();
    }

#pragma unroll
    for (int rf = 0; rf < 5; ++rf)
#pragma unroll
      for (int ri = 0; ri < 4; ++ri) {
        int row = wv * 80 + rf * 16 + (lane >> 4) * 4 + ri;
        int grow = r0 + row;
        if (grow < count) {
#pragma unroll
          for (int cf = 0; cf < 2; ++cf)
            buf[(size_t)(base + grow) * HD + colbase + cf * 16 + l15] = acc[rf][cf][ri];
        }
      }
  }
#undef G2_AFLOAD
#undef G2_WLOAD
#undef G2_WSTORE
#undef G2_MFMA
}

// -------------------------------------------------------------- k_reduce ---
__global__ void k_reduce(const float* __restrict__ buf, const int* __restrict__ invp,
                         float* __restrict__ out) {
  int t = blockIdx.x;
  int col = threadIdx.x * 4;
  int p0 = invp[t * 4 + 0], p1 = invp[t * 4 + 1];
  int p2 = invp[t * 4 + 2], p3 = invp[t * 4 + 3];
  fvec4 s = *(const fvec4*)(buf + (size_t)p0 * HD + col);
  s += *(const fvec4*)(buf + (size_t)p1 * HD + col);
  s += *(const fvec4*)(buf + (size_t)p2 * HD + col);
  s += *(const fvec4*)(buf + (size_t)p3 * HD + col);
  *(fvec4*)(out + (size_t)t * HD + col) = s;
}

// ------------------------------------------------------------------ host ---
extern "C" void kernel_launch(void* const* d_in, const int* in_sizes, int n_in,
                              void* d_out, int out_size, void* d_ws, size_t ws_size,
                              hipStream_t stream) {
  const float* x  = (const float*)d_in[0];
  const float* gw = (const float*)d_in[1];
  const float* w1 = (const float*)d_in[2];
  const float* w3 = (const float*)d_in[3];
  const float* w2 = (const float*)d_in[4];
  const float* eb = (const float*)d_in[5];
  float* out = (float*)d_out;

  char* ws = (char*)d_ws;
  int*   counts   = (int*)(ws);               // [32]   (zeroed)
  int*   offsets  = (int*)(ws + 256);         // [33]
  int*   topk_ids = (int*)(ws + 4096);        // [8192]
  float* topk_w   = (float*)(ws + 36864);     // [8192]
  int*   pairTok  = (int*)(ws + 69632);       // [8192]
  float* pairW    = (float*)(ws + 102400);    // [8192]
  int*   invp     = (int*)(ws + 135168);      // [8192]
  // Region A (33.55 MB): Xp (16.78 MB, dead after gemm1) overlaid by buf (f32)
  u16t*  Xp   = (u16t*)(ws + 262144);
  float* buf  = (float*)(ws + 262144);
  u16t*  Abuf = (u16t*)(ws + 262144 + 33554432);   // 12.58 MB swizzled bf16
  // total ~46.4 MB

  hipMemsetAsync(counts, 0, 4096, stream);
  k_router <<<512, 256, 0, stream>>>(x, gw, eb, topk_ids, topk_w, counts);
  k_bucket <<<1, 256, 0, stream>>>(topk_ids, topk_w, counts, offsets, pairTok, pairW, invp);
  k_permute<<<512, 256, 0, stream>>>(x, pairTok, Xp);
  k_gemm1  <<<768, 256, 0, stream>>>(Xp, w1, w3, counts, offsets, pairW, Abuf);
  k_gemm2  <<<1024, 256, 0, stream>>>(Abuf, w2, counts, offsets, buf);
  k_reduce <<<2048, 256, 0, stream>>>(buf, invp, out);
}